// Round 1
// baseline (2559.463 us; speedup 1.0000x reference)
//
#include <hip/hip_runtime.h>
#include <hip/hip_bf16.h>
#include <hip/hip_cooperative_groups.h>
#include <cstddef>

namespace cg = cooperative_groups;

#define HD 512

typedef short s8v __attribute__((ext_vector_type(8)));
typedef short s4v __attribute__((ext_vector_type(4)));
typedef float fx4 __attribute__((ext_vector_type(4)));

#define MFMA(a, b, c) __builtin_amdgcn_mfma_f32_16x16x32_bf16((a), (b), (c), 0, 0, 0)

__device__ __forceinline__ unsigned short f2bf(float f) {
  unsigned int u = __float_as_uint(f);
  unsigned int r = (u + 0x7fffu + ((u >> 16) & 1u)) >> 16;
  return (unsigned short)r;
}
__device__ __forceinline__ float bf2f(unsigned short u) {
  return __uint_as_float(((unsigned int)u) << 16);
}

// Swizzled B-operand layout: element (k,n) of a K x N matrix ->
// chunk = (ntile*KT + kt), within chunk: lane = ((k&31)>>3)<<4 | (n&15), i = k&7
__device__ __forceinline__ size_t swz_off(int k, int n, int KT) {
  int kt = k >> 5, kr = k & 31;
  int nt = n >> 4, nr = n & 15;
  int lane = ((kr >> 3) << 4) | nr;
  int i = kr & 7;
  return ((((size_t)nt * KT + kt) * 64 + lane) << 3) + i;
}

// ---------------- pack weights into bf16 swizzled layouts ----------------
__global__ void pack_kernel(const float* w_r, const float* wz, const float* wh,
                            const float* ur, const float* wo,
                            unsigned short* W1, unsigned short* WZB, unsigned short* WHB,
                            unsigned short* WUR, unsigned short* WO) {
  int idx = blockIdx.x * blockDim.x + threadIdx.x;
  int stride = gridDim.x * blockDim.x;
  for (int t = idx; t < 512 * 1536; t += stride) {
    int k = t / 1536, n = t - k * 1536;
    float v;
    if (n < 512) v = w_r[k * 512 + n];
    else if (n < 1024) v = wz[k * 512 + (n - 512)];
    else v = wh[k * 512 + (n - 1024)];
    W1[swz_off(k, n, 16)] = f2bf(v);
  }
  for (int t = idx; t < 512 * 512; t += stride) {
    int k = t >> 9, n = t & 511;
    size_t o = swz_off(k, n, 16);
    WZB[o] = f2bf(wz[(512 + k) * 512 + n]);
    WHB[o] = f2bf(wh[(512 + k) * 512 + n]);
    WUR[o] = f2bf(ur[k * 512 + n]);
  }
  for (int t = idx; t < 1024 * 512; t += stride) {
    int k = t >> 9, n = t & 511;
    WO[swz_off(k, n, 32)] = f2bf(wo[k * 512 + n]);
  }
}

// ---------------- embedding gather: x_bf[node] = bf16(emb[wid[node]]) ----------------
__global__ void embed_kernel(const int* wid, const float* emb, unsigned short* x_bf, int BN) {
  int idx = blockIdx.x * blockDim.x + threadIdx.x;
  int stride = gridDim.x * blockDim.x;
  int total = BN * (HD / 8);
  for (int t = idx; t < total; t += stride) {
    int nrow = t >> 6;
    int c8 = (t & 63) << 3;
    int w = wid[nrow];
    const float4* s = (const float4*)(emb + (size_t)w * HD + c8);
    float4 v0 = s[0], v1 = s[1];
    s8v o;
    o[0] = (short)f2bf(v0.x); o[1] = (short)f2bf(v0.y);
    o[2] = (short)f2bf(v0.z); o[3] = (short)f2bf(v0.w);
    o[4] = (short)f2bf(v1.x); o[5] = (short)f2bf(v1.y);
    o[6] = (short)f2bf(v1.z); o[7] = (short)f2bf(v1.w);
    *(s8v*)&x_bf[(size_t)nrow * HD + c8] = o;
  }
}

// ---------------- schedule: per-tree wavefront rounds from preds ----------------
// sched[0]=R, sched[1+r]=cnt_r, sched[33 + r*32 + j] = per-tree local edge id
__global__ void schedule_kernel(const int* preds, int E, int Epc, int P, int* sched) {
  __shared__ int rnd[64];
  int t = threadIdx.x;
  rnd[t] = -1;
  __syncthreads();
  for (int it = 0; it <= Epc; ++it) {
    int newv = -1;
    if (t < Epc && rnd[t] < 0) {
      int mx = 0;
      bool ready = true;
      for (int q = 0; q < P; ++q) {
        int pe = preds[t * P + q];
        if (pe < E) {  // valid pred (tree-0 ids are < Epc)
          int rp = rnd[pe];
          if (rp < 0) ready = false;
          else if (rp + 1 > mx) mx = rp + 1;
        }
      }
      if (ready) newv = mx;
    }
    __syncthreads();
    if (newv >= 0) rnd[t] = newv;
    __syncthreads();
  }
  if (t == 0) {
    int R = 0;
    for (int e = 0; e < Epc; ++e) if (rnd[e] + 1 > R) R = rnd[e] + 1;
    if (R > 31) R = 31;
    sched[0] = R;
    for (int r = 0; r < R; ++r) {
      int c = 0;
      for (int e = 0; e < Epc; ++e) if (rnd[e] == r) { sched[33 + r * 32 + c] = e; ++c; }
      sched[1 + r] = c;
    }
  }
}

// ---------------- precompute GEMM: XP = x_bf @ [w_r | wz_top | wh_top] ----------------
__global__ __launch_bounds__(256) void gemm_pre_kernel(const unsigned short* x_bf,
                                                       const unsigned short* W1,
                                                       unsigned short* XP, int BN) {
  __shared__ unsigned short lA[32 * 40];
  int bt = blockIdx.x;
  int nM = BN >> 5;
  int mt = bt / 6, nt = bt - mt * 6;
  if (mt >= nM) return;
  int tid = threadIdx.x, lane = tid & 63, w = tid >> 6;
  int wm = w & 1, wn = w >> 1;
  int m0 = mt << 5;
  fx4 acc[8];
#pragma unroll
  for (int n = 0; n < 8; n++) { acc[n][0]=0.f; acc[n][1]=0.f; acc[n][2]=0.f; acc[n][3]=0.f; }
  int srow = tid >> 3, squad = tid & 7;
  int arow = (wm << 4) | (lane & 15), k8 = (lane >> 4) << 3;
  for (int kt = 0; kt < 16; ++kt) {
    const unsigned short* gp = x_bf + (size_t)(m0 + srow) * HD + (kt << 5) + (squad << 2);
    *(s4v*)&lA[srow * 40 + (squad << 2)] = *(const s4v*)gp;
    __syncthreads();
    s8v a = *(const s8v*)&lA[arow * 40 + k8];
#pragma unroll
    for (int n = 0; n < 8; n++) {
      int ntile = nt * 16 + wn * 8 + n;
      const s8v* bp = (const s8v*)(W1 + ((((size_t)ntile * 16 + kt) * 64 + lane) << 3));
      acc[n] = MFMA(a, *bp, acc[n]);
    }
    __syncthreads();
  }
#pragma unroll
  for (int n = 0; n < 8; n++) {
    int gcol = (nt << 8) + (wn << 7) + (n << 4) + (lane & 15);
#pragma unroll
    for (int q = 0; q < 4; q++) {
      int row = (wm << 4) + ((lane >> 4) << 2) + q;
      XP[(size_t)(m0 + row) * 1536 + gcol] = f2bf(acc[n][q]);
    }
  }
}

// ---------------- cooperative tree kernel ----------------
struct TreeP {
  const int* preds;
  const int* edge_src;
  const float* ur_b;
  const float* wz_b;
  const float* wh_b;
  const unsigned short* XP;
  const unsigned short* WZB;
  const unsigned short* WHB;
  const unsigned short* WUR;
  unsigned short* A2;
  unsigned short* h_bf;
  unsigned short* u_bf;
  float* h;
  const int* sched;
  int B, Epc, P, E;
};

__global__ void tree_kernel(TreeP p) {
  cg::grid_group grid = cg::this_grid();
  __shared__ unsigned short lA[2][32 * 40];
  const int tid = threadIdx.x;
  const int lane = tid & 63;
  const int w = tid >> 6;
  const int wm = w & 1, wn = w >> 1;
  const int waveId = blockIdx.x * 4 + w;
  const int totalWaves = gridDim.x * 4;
  const int R = p.sched[0];
  for (int r = 0; r < R; ++r) {
    const int cnt = p.sched[1 + r];
    const int M = cnt * p.B;
    const int padM = (M + 31) & ~31;
    const int* lst = p.sched + 33 + r * 32;
    // ---- phase A: gather preds, compute sum_h (f32 -> h), sum_g; A2 = [sumh_bf|sumg_bf]
    for (int m = waveId; m < padM; m += totalWaves) {
      const int c0 = lane << 3;
      int j = m / p.B;
      if (j >= cnt) {
        s8v z;
#pragma unroll
        for (int i = 0; i < 8; i++) z[i] = 0;
        *(s8v*)&p.A2[(size_t)m * 1024 + c0] = z;
        *(s8v*)&p.A2[(size_t)m * 1024 + 512 + c0] = z;
        continue;
      }
      int b = m - j * p.B;
      int e = b * p.Epc + lst[j];
      int src = p.edge_src[e];
      float sh[8], sg[8];
#pragma unroll
      for (int i = 0; i < 8; i++) { sh[i] = 0.f; sg[i] = 0.f; }
      s8v xr8 = *(const s8v*)&p.XP[(size_t)src * 1536 + c0];
      float xb[8], ub[8];
#pragma unroll
      for (int i = 0; i < 8; i++) {
        xb[i] = bf2f((unsigned short)xr8[i]);
        ub[i] = p.ur_b[c0 + i];
      }
      for (int t = 0; t < p.P; ++t) {
        int pe = p.preds[(size_t)e * p.P + t];
        if (pe >= p.E) continue;
        const float4* hp = (const float4*)(p.h + (size_t)pe * HD + c0);
        float4 h0 = hp[0], h1 = hp[1];
        s8v u8 = *(const s8v*)&p.u_bf[(size_t)pe * HD + c0];
        float hv[8] = {h0.x, h0.y, h0.z, h0.w, h1.x, h1.y, h1.z, h1.w};
#pragma unroll
        for (int i = 0; i < 8; i++) {
          float rr = 1.f / (1.f + __expf(-(xb[i] + bf2f((unsigned short)u8[i]) + ub[i])));
          sh[i] += hv[i];
          sg[i] += rr * hv[i];
        }
      }
      *(float4*)(p.h + (size_t)e * HD + c0) = make_float4(sh[0], sh[1], sh[2], sh[3]);
      *(float4*)(p.h + (size_t)e * HD + c0 + 4) = make_float4(sh[4], sh[5], sh[6], sh[7]);
      s8v shb, sgb;
#pragma unroll
      for (int i = 0; i < 8; i++) { shb[i] = (short)f2bf(sh[i]); sgb[i] = (short)f2bf(sg[i]); }
      *(s8v*)&p.A2[(size_t)m * 1024 + c0] = shb;
      *(s8v*)&p.A2[(size_t)m * 1024 + 512 + c0] = sgb;
    }
    grid.sync();
    // ---- phase B: dual GEMM (sumh@WZB, sumg@WHB) + gate epilogue -> h, h_bf
    const int nTiles = (padM >> 5) * 2;
    for (int bt = blockIdx.x; bt < nTiles; bt += gridDim.x) {
      const int mt = bt >> 1, nt = bt & 1;
      const int m0 = mt << 5;
      fx4 ac1[8], ac2[8];
#pragma unroll
      for (int n = 0; n < 8; n++) {
        ac1[n][0]=0.f; ac1[n][1]=0.f; ac1[n][2]=0.f; ac1[n][3]=0.f;
        ac2[n][0]=0.f; ac2[n][1]=0.f; ac2[n][2]=0.f; ac2[n][3]=0.f;
      }
      const int srow = tid >> 3, squad = tid & 7;
      const int arow = (wm << 4) | (lane & 15);
      const int k8 = (lane >> 4) << 3;
      for (int kt = 0; kt < 16; ++kt) {
        const unsigned short* g1 = p.A2 + (size_t)(m0 + srow) * 1024 + (kt << 5) + (squad << 2);
        *(s4v*)&lA[0][srow * 40 + (squad << 2)] = *(const s4v*)g1;
        *(s4v*)&lA[1][srow * 40 + (squad << 2)] = *(const s4v*)(g1 + 512);
        __syncthreads();
        s8v a1 = *(const s8v*)&lA[0][arow * 40 + k8];
        s8v a2 = *(const s8v*)&lA[1][arow * 40 + k8];
#pragma unroll
        for (int n = 0; n < 8; n++) {
          const int ntile = (nt << 4) + (wn << 3) + n;
          const size_t boff = ((((size_t)ntile << 4) + kt) * 64 + lane) << 3;
          ac1[n] = MFMA(a1, *(const s8v*)(p.WZB + boff), ac1[n]);
          ac2[n] = MFMA(a2, *(const s8v*)(p.WHB + boff), ac2[n]);
        }
        __syncthreads();
      }
#pragma unroll
      for (int q = 0; q < 4; q++) {
        const int row = (wm << 4) + ((lane >> 4) << 2) + q;
        const int m = m0 + row;
        const int j = m / p.B;
        if (j >= cnt) continue;
        const int b = m - j * p.B;
        const int e = b * p.Epc + lst[j];
        const int src = p.edge_src[e];
#pragma unroll
        for (int n = 0; n < 8; n++) {
          const int col = (nt << 8) + (wn << 7) + (n << 4) + (lane & 15);
          float zpre = ac1[n][q] + bf2f(p.XP[(size_t)src * 1536 + 512 + col]) + p.wz_b[col];
          float hpre = ac2[n][q] + bf2f(p.XP[(size_t)src * 1536 + 1024 + col]) + p.wh_b[col];
          float zz = 1.f / (1.f + __expf(-zpre));
          float e2 = __expf(2.f * hpre);
          float th = 1.f - 2.f / (e2 + 1.f);
          size_t off = (size_t)e * HD + col;
          float hn = (1.f - zz) * p.h[off] + zz * th;
          p.h[off] = hn;
          p.h_bf[off] = f2bf(hn);
        }
      }
    }
    grid.sync();
    // ---- phase C: u = h_bf @ WUR for this round's edges
    for (int bt = blockIdx.x; bt < nTiles; bt += gridDim.x) {
      const int mt = bt >> 1, nt = bt & 1;
      const int m0 = mt << 5;
      fx4 ac[8];
#pragma unroll
      for (int n = 0; n < 8; n++) { ac[n][0]=0.f; ac[n][1]=0.f; ac[n][2]=0.f; ac[n][3]=0.f; }
      const int srow = tid >> 3, squad = tid & 7;
      const int arow = (wm << 4) | (lane & 15);
      const int k8 = (lane >> 4) << 3;
      const int ms = m0 + srow;
      const int js = ms / p.B;
      const unsigned short* ap = nullptr;
      if (js < cnt) {
        const int bs = ms - js * p.B;
        ap = p.h_bf + (size_t)(bs * p.Epc + lst[js]) * HD;
      }
      for (int kt = 0; kt < 16; ++kt) {
        s4v av;
        if (ap) av = *(const s4v*)(ap + (kt << 5) + (squad << 2));
        else {
#pragma unroll
          for (int i = 0; i < 4; i++) av[i] = 0;
        }
        *(s4v*)&lA[0][srow * 40 + (squad << 2)] = av;
        __syncthreads();
        s8v a = *(const s8v*)&lA[0][arow * 40 + k8];
#pragma unroll
        for (int n = 0; n < 8; n++) {
          const int ntile = (nt << 4) + (wn << 3) + n;
          const size_t boff = ((((size_t)ntile << 4) + kt) * 64 + lane) << 3;
          ac[n] = MFMA(a, *(const s8v*)(p.WUR + boff), ac[n]);
        }
        __syncthreads();
      }
#pragma unroll
      for (int q = 0; q < 4; q++) {
        const int row = (wm << 4) + ((lane >> 4) << 2) + q;
        const int m = m0 + row;
        const int j = m / p.B;
        if (j >= cnt) continue;
        const int b = m - j * p.B;
        const int e = b * p.Epc + lst[j];
#pragma unroll
        for (int n = 0; n < 8; n++) {
          const int col = (nt << 8) + (wn << 7) + (n << 4) + (lane & 15);
          p.u_bf[(size_t)e * HD + col] = f2bf(ac[n][q]);
        }
      }
    }
    grid.sync();
  }
}

// ---------------- root: gather [x_root | sum h(root children)] then GEMM+relu ----------------
__global__ void root_gather_kernel(const int* root_nodes, const int* root_in,
                                   const unsigned short* x_bf, const float* h,
                                   unsigned short* Aroot, int B, int R0) {
  int lane = threadIdx.x & 63;
  int waveId = blockIdx.x * (blockDim.x >> 6) + (threadIdx.x >> 6);
  int totalWaves = gridDim.x * (blockDim.x >> 6);
  for (int b = waveId; b < B; b += totalWaves) {
    int c0 = lane << 3;
    int nd = root_nodes[b];
    *(s8v*)&Aroot[(size_t)b * 1024 + c0] = *(const s8v*)&x_bf[(size_t)nd * HD + c0];
    float s[8];
#pragma unroll
    for (int i = 0; i < 8; i++) s[i] = 0.f;
    for (int t = 0; t < R0; ++t) {
      int e = root_in[b * R0 + t];
      const float4* hp = (const float4*)(h + (size_t)e * HD + c0);
      float4 h0 = hp[0], h1 = hp[1];
      s[0] += h0.x; s[1] += h0.y; s[2] += h0.z; s[3] += h0.w;
      s[4] += h1.x; s[5] += h1.y; s[6] += h1.z; s[7] += h1.w;
    }
    s8v sb;
#pragma unroll
    for (int i = 0; i < 8; i++) sb[i] = (short)f2bf(s[i]);
    *(s8v*)&Aroot[(size_t)b * 1024 + 512 + c0] = sb;
  }
}

__global__ __launch_bounds__(256) void gemm_root_kernel(const unsigned short* Aroot,
                                                        const unsigned short* WO,
                                                        const float* wo_b, float* out, int B) {
  __shared__ unsigned short lA[32 * 40];
  int tid = threadIdx.x, lane = tid & 63, w = tid >> 6;
  int wm = w & 1, wn = w >> 1;
  int bt = blockIdx.x;
  int mt = bt >> 1, nt = bt & 1;
  int m0 = mt << 5;
  fx4 ac[8];
#pragma unroll
  for (int n = 0; n < 8; n++) { ac[n][0]=0.f; ac[n][1]=0.f; ac[n][2]=0.f; ac[n][3]=0.f; }
  int srow = tid >> 3, squad = tid & 7;
  int arow = (wm << 4) | (lane & 15), k8 = (lane >> 4) << 3;
  for (int kt = 0; kt < 32; ++kt) {
    const unsigned short* g = Aroot + (size_t)(m0 + srow) * 1024 + (kt << 5) + (squad << 2);
    *(s4v*)&lA[srow * 40 + (squad << 2)] = *(const s4v*)g;
    __syncthreads();
    s8v a = *(const s8v*)&lA[arow * 40 + k8];
#pragma unroll
    for (int n = 0; n < 8; n++) {
      int ntile = (nt << 4) + (wn << 3) + n;
      size_t boff = ((((size_t)ntile * 32) + kt) * 64 + lane) << 3;
      ac[n] = MFMA(a, *(const s8v*)(WO + boff), ac[n]);
    }
    __syncthreads();
  }
#pragma unroll
  for (int q = 0; q < 4; q++) {
    int row = (wm << 4) + ((lane >> 4) << 2) + q;
    int m = m0 + row;
#pragma unroll
    for (int n = 0; n < 8; n++) {
      int col = (nt << 8) + (wn << 7) + (n << 4) + (lane & 15);
      float v = ac[n][q] + wo_b[col];
      out[(size_t)m * HD + col] = v > 0.f ? v : 0.f;
    }
  }
}

extern "C" void kernel_launch(void* const* d_in, const int* in_sizes, int n_in,
                              void* d_out, int out_size, void* d_ws, size_t ws_size,
                              hipStream_t stream) {
  const int* wid = (const int*)d_in[0];
  const int* edge_src = (const int*)d_in[1];
  const int* preds = (const int*)d_in[2];
  const int* root_in = (const int*)d_in[4];
  const int* root_nodes = (const int*)d_in[5];
  const float* emb = (const float*)d_in[6];
  const float* w_r = (const float*)d_in[7];
  const float* ur_w = (const float*)d_in[8];
  const float* ur_b = (const float*)d_in[9];
  const float* wz_w = (const float*)d_in[10];
  const float* wz_b = (const float*)d_in[11];
  const float* wh_w = (const float*)d_in[12];
  const float* wh_b = (const float*)d_in[13];
  const float* wo_w = (const float*)d_in[14];
  const float* wo_b = (const float*)d_in[15];

  const int BN = in_sizes[0];
  const int E = in_sizes[1];
  const int Bt = in_sizes[5];
  const int Epc = E / Bt;
  const int P = in_sizes[2] / (E + 1);
  const int R0 = in_sizes[4] / Bt;

  float* h = (float*)d_out;

  char* wp = (char*)d_ws;
  auto alloc = [&](size_t bytes) {
    char* r = wp;
    wp += (bytes + 255) & ~(size_t)255;
    return r;
  };
  unsigned short* XP = (unsigned short*)alloc((size_t)BN * 1536 * 2);
  unsigned short* x_bf = (unsigned short*)alloc((size_t)BN * HD * 2);
  unsigned short* h_bf = (unsigned short*)alloc((size_t)E * HD * 2);
  unsigned short* u_bf = (unsigned short*)alloc((size_t)E * HD * 2);
  unsigned short* A2 = (unsigned short*)alloc((size_t)E * 1024 * 2);
  unsigned short* W1 = (unsigned short*)alloc((size_t)512 * 1536 * 2);
  unsigned short* WZB = (unsigned short*)alloc((size_t)512 * 512 * 2);
  unsigned short* WHB = (unsigned short*)alloc((size_t)512 * 512 * 2);
  unsigned short* WUR = (unsigned short*)alloc((size_t)512 * 512 * 2);
  unsigned short* WO = (unsigned short*)alloc((size_t)1024 * 512 * 2);
  unsigned short* Aroot = (unsigned short*)alloc((size_t)Bt * 1024 * 2);
  int* sched = (int*)alloc(8192);

  hipLaunchKernelGGL(pack_kernel, dim3(2048), dim3(256), 0, stream,
                     w_r, wz_w, wh_w, ur_w, wo_w, W1, WZB, WHB, WUR, WO);
  hipLaunchKernelGGL(embed_kernel, dim3(4096), dim3(256), 0, stream, wid, emb, x_bf, BN);
  hipLaunchKernelGGL(schedule_kernel, dim3(1), dim3(64), 0, stream, preds, E, Epc, P, sched);
  hipLaunchKernelGGL(gemm_pre_kernel, dim3((BN / 32) * 6), dim3(256), 0, stream, x_bf, W1, XP, BN);

  TreeP tp;
  tp.preds = preds; tp.edge_src = edge_src;
  tp.ur_b = ur_b; tp.wz_b = wz_b; tp.wh_b = wh_b;
  tp.XP = XP; tp.WZB = WZB; tp.WHB = WHB; tp.WUR = WUR;
  tp.A2 = A2; tp.h_bf = h_bf; tp.u_bf = u_bf;
  tp.h = h; tp.sched = sched;
  tp.B = Bt; tp.Epc = Epc; tp.P = P; tp.E = E;

  int dev = 0;
  hipGetDevice(&dev);
  int maxBlk = 0, nCU = 0;
  hipOccupancyMaxActiveBlocksPerMultiprocessor(&maxBlk, (const void*)tree_kernel, 256, 0);
  hipDeviceGetAttribute(&nCU, hipDeviceAttributeMultiprocessorCount, dev);
  long G = (long)maxBlk * (long)nCU;
  if (G < 1) G = 1;
  if (G > 4096) G = 4096;
  void* args[] = {&tp};
  hipLaunchCooperativeKernel((const void*)tree_kernel, dim3((unsigned)G), dim3(256), args, 0, stream);

  hipLaunchKernelGGL(root_gather_kernel, dim3(512), dim3(256), 0, stream,
                     root_nodes, root_in, x_bf, h, Aroot, Bt, R0);
  hipLaunchKernelGGL(gemm_root_kernel, dim3((Bt / 32) * 2), dim3(256), 0, stream,
                     Aroot, WO, wo_b, h + (size_t)E * HD, Bt);
}

// Round 3
// 1814.740 us; speedup vs baseline: 1.4104x; 1.4104x over previous
//
#include <hip/hip_runtime.h>
#include <hip/hip_bf16.h>
#include <cstddef>

#define HD 512

typedef short s8v __attribute__((ext_vector_type(8)));
typedef short s4v __attribute__((ext_vector_type(4)));
typedef float fx4 __attribute__((ext_vector_type(4)));

#define MFMA(a, b, c) __builtin_amdgcn_mfma_f32_16x16x32_bf16((a), (b), (c), 0, 0, 0)

__device__ __forceinline__ unsigned short f2bf(float f) {
  unsigned int u = __float_as_uint(f);
  unsigned int r = (u + 0x7fffu + ((u >> 16) & 1u)) >> 16;
  return (unsigned short)r;
}
__device__ __forceinline__ float bf2f(unsigned short u) {
  return __uint_as_float(((unsigned int)u) << 16);
}

// Swizzled B-operand layout for 16x16x32 MFMA (R1-proven):
// element (k,n) -> chunk (ntile*KT + kt); lane = ((k&31)>>3)<<4 | (n&15); i = k&7
__device__ __forceinline__ size_t swz_off(int k, int n, int KT) {
  int kt = k >> 5, kr = k & 31;
  int nt = n >> 4, nr = n & 15;
  int lane = ((kr >> 3) << 4) | nr;
  int i = kr & 7;
  return ((((size_t)nt * KT + kt) * 64 + lane) << 3) + i;
}

// ---------------- pack weights ----------------
__global__ void pack_kernel(const float* w_r, const float* ur, const float* wz, const float* wh,
                            const float* wo,
                            unsigned short* WR, unsigned short* WUR, unsigned short* WZf,
                            unsigned short* WHf, unsigned short* WO) {
  int idx = blockIdx.x * blockDim.x + threadIdx.x;
  int stride = gridDim.x * blockDim.x;
  for (int t = idx; t < 512 * 512; t += stride) {
    int k = t >> 9, n = t & 511;
    size_t o = swz_off(k, n, 16);
    WR[o] = f2bf(w_r[t]);
    WUR[o] = f2bf(ur[t]);
  }
  for (int t = idx; t < 1024 * 512; t += stride) {
    int k = t >> 9, n = t & 511;
    size_t o = swz_off(k, n, 32);
    WZf[o] = f2bf(wz[t]);
    WHf[o] = f2bf(wh[t]);
    WO[o] = f2bf(wo[t]);
  }
}

// ---------------- embedding gather ----------------
__global__ void embed_kernel(const int* wid, const float* emb, unsigned short* x_bf, int BN) {
  int idx = blockIdx.x * blockDim.x + threadIdx.x;
  int stride = gridDim.x * blockDim.x;
  int total = BN * (HD / 8);
  for (int t = idx; t < total; t += stride) {
    int nrow = t >> 6;
    int c8 = (t & 63) << 3;
    int w = wid[nrow];
    const float4* s = (const float4*)(emb + (size_t)w * HD + c8);
    float4 v0 = s[0], v1 = s[1];
    s8v o;
    o[0] = (short)f2bf(v0.x); o[1] = (short)f2bf(v0.y);
    o[2] = (short)f2bf(v0.z); o[3] = (short)f2bf(v0.w);
    o[4] = (short)f2bf(v1.x); o[5] = (short)f2bf(v1.y);
    o[6] = (short)f2bf(v1.z); o[7] = (short)f2bf(v1.w);
    *(s8v*)&x_bf[(size_t)nrow * HD + c8] = o;
  }
}

// ---------------- schedule (R1-proven + zero-fill for unused rounds) ----------------
__global__ void schedule_kernel(const int* preds, int E, int Epc, int P, int* sched) {
  __shared__ int rnd[64];
  int t = threadIdx.x;
  rnd[t] = -1;
  __syncthreads();
  for (int it = 0; it <= Epc; ++it) {
    int newv = -1;
    if (t < Epc && rnd[t] < 0) {
      int mx = 0;
      bool ready = true;
      for (int q = 0; q < P; ++q) {
        int pe = preds[t * P + q];
        if (pe < E) {
          int rp = rnd[pe];
          if (rp < 0) ready = false;
          else if (rp + 1 > mx) mx = rp + 1;
        }
      }
      if (ready) newv = mx;
    }
    __syncthreads();
    if (newv >= 0) rnd[t] = newv;
    __syncthreads();
  }
  if (t == 0) {
    int R = 0;
    for (int e = 0; e < Epc; ++e) if (rnd[e] + 1 > R) R = rnd[e] + 1;
    if (R > 31) R = 31;
    sched[0] = R;
    for (int r = 0; r < 31; ++r) {
      int c = 0;
      if (r < R) {
        for (int e = 0; e < Epc; ++e) if (rnd[e] == r) { sched[33 + r * 32 + c] = e; ++c; }
      }
      sched[1 + r] = c;
    }
  }
}

// ---------------- XR = x_bf @ w_r ----------------
__global__ __launch_bounds__(256) void gemm_xr_kernel(const unsigned short* x_bf,
                                                      const unsigned short* WR,
                                                      unsigned short* XR, int BN) {
  __shared__ unsigned short lA[32 * 40];
  int bt = blockIdx.x;
  int mt = bt >> 1, nt = bt & 1;
  int tid = threadIdx.x, lane = tid & 63, w = tid >> 6;
  int wm = w & 1, wn = w >> 1;
  int m0 = mt << 5;
  fx4 acc[8];
#pragma unroll
  for (int n = 0; n < 8; n++) { acc[n][0]=0.f; acc[n][1]=0.f; acc[n][2]=0.f; acc[n][3]=0.f; }
  int srow = tid >> 3, squad = tid & 7;
  int arow = (wm << 4) | (lane & 15), k8 = (lane >> 4) << 3;
  for (int kt = 0; kt < 16; ++kt) {
    const unsigned short* gp = x_bf + (size_t)(m0 + srow) * HD + (kt << 5) + (squad << 2);
    *(s4v*)&lA[srow * 40 + (squad << 2)] = *(const s4v*)gp;
    __syncthreads();
    s8v a = *(const s8v*)&lA[arow * 40 + k8];
#pragma unroll
    for (int n = 0; n < 8; n++) {
      int ntile = (nt << 4) + (wn << 3) + n;
      const s8v* bp = (const s8v*)(WR + ((((size_t)ntile << 4) + kt) * 64 + lane) * 8);
      acc[n] = MFMA(a, *bp, acc[n]);
    }
    __syncthreads();
  }
#pragma unroll
  for (int n = 0; n < 8; n++) {
    int gcol = (nt << 8) + (wn << 7) + (n << 4) + (lane & 15);
#pragma unroll
    for (int q = 0; q < 4; q++) {
      int row = (wm << 4) + ((lane >> 4) << 2) + q;
      XR[(size_t)(m0 + row) * 512 + gcol] = f2bf(acc[n][q]);
    }
  }
}

// ---------------- per-round kernel: phase A + z/h GEMM + u GEMM, stripe-local ----------------
struct RP {
  const int* sched;
  const int* preds;
  const int* edge_src;
  const float* ur_b;
  const float* wz_b;
  const float* wh_b;
  const unsigned short* x_bf;
  const unsigned short* XR;
  const unsigned short* WZf;
  const unsigned short* WHf;
  const unsigned short* WUR;
  unsigned short* A2h;
  unsigned short* A2g;
  unsigned short* h_bf;
  unsigned short* u_bf;
  float* h;
  int B, Epc, P, E;
};

__global__ __launch_bounds__(256) void round_kernel(RP p, int r) {
  const int cnt = p.sched[1 + r];
  if (cnt == 0) return;
  const int M = cnt * p.B;
  const int nStripes = M >> 5;
  const int* lst = p.sched + 33 + r * 32;
  __shared__ unsigned short lA0[32 * 40];
  __shared__ unsigned short lA1[32 * 40];
  __shared__ int eL[32];
  __shared__ int sL[32];
  const int tid = threadIdx.x, lane = tid & 63, w = tid >> 6;
  const int wm = w & 1, wn = w >> 1;
  const int srow = tid >> 3, squad = tid & 7;
  const int arow = (wm << 4) | (lane & 15), k8 = (lane >> 4) << 3;

  for (int s = blockIdx.x; s < nStripes; s += gridDim.x) {
    const int m0 = s << 5;
    // ---- phase A: rows m0..m0+32; wave w owns rows w*8..w*8+8
    for (int ri = 0; ri < 8; ++ri) {
      const int lrow = (w << 3) + ri;
      const int m = m0 + lrow;
      const int j = m / p.B;
      const int b = m - j * p.B;
      const int e = b * p.Epc + lst[j];
      const int src = p.edge_src[e];
      if (lane == 0) { eL[lrow] = e; sL[lrow] = src; }
      const int c0 = lane << 3;
      const s8v xr8 = *(const s8v*)&p.XR[(size_t)src * 512 + c0];
      float xb[8], ub[8], sh[8], sg[8];
#pragma unroll
      for (int i = 0; i < 8; i++) {
        xb[i] = bf2f((unsigned short)xr8[i]);
        ub[i] = p.ur_b[c0 + i];
        sh[i] = 0.f; sg[i] = 0.f;
      }
      for (int t = 0; t < p.P; ++t) {
        const int pe = p.preds[(size_t)e * p.P + t];
        if (pe >= p.E) continue;
        const float4* hp = (const float4*)(p.h + (size_t)pe * 512 + c0);
        const float4 h0 = hp[0], h1 = hp[1];
        const s8v u8 = *(const s8v*)&p.u_bf[(size_t)pe * 512 + c0];
        const float hv[8] = {h0.x, h0.y, h0.z, h0.w, h1.x, h1.y, h1.z, h1.w};
#pragma unroll
        for (int i = 0; i < 8; i++) {
          const float rr = 1.f / (1.f + __expf(-(xb[i] + bf2f((unsigned short)u8[i]) + ub[i])));
          sh[i] += hv[i];
          sg[i] += rr * hv[i];
        }
      }
      *(float4*)(p.h + (size_t)e * 512 + c0) = make_float4(sh[0], sh[1], sh[2], sh[3]);
      *(float4*)(p.h + (size_t)e * 512 + c0 + 4) = make_float4(sh[4], sh[5], sh[6], sh[7]);
      s8v shb, sgb;
#pragma unroll
      for (int i = 0; i < 8; i++) { shb[i] = (short)f2bf(sh[i]); sgb[i] = (short)f2bf(sg[i]); }
      *(s8v*)&p.A2h[(size_t)m * 512 + c0] = shb;
      *(s8v*)&p.A2g[(size_t)m * 512 + c0] = sgb;
    }
    __syncthreads();
    // ---- phase B: dual GEMM ([x_src | sumh] @ WZf, [x_src | sumg] @ WHf), K=1024
    for (int nt = 0; nt < 2; ++nt) {
      fx4 ac1[8], ac2[8];
#pragma unroll
      for (int n = 0; n < 8; n++) {
        ac1[n][0]=0.f; ac1[n][1]=0.f; ac1[n][2]=0.f; ac1[n][3]=0.f;
        ac2[n][0]=0.f; ac2[n][1]=0.f; ac2[n][2]=0.f; ac2[n][3]=0.f;
      }
      for (int kt = 0; kt < 32; ++kt) {
        if (kt < 16) {
          const unsigned short* s0 = p.x_bf + (size_t)sL[srow] * 512 + (kt << 5) + (squad << 2);
          const s4v v = *(const s4v*)s0;
          *(s4v*)&lA0[srow * 40 + (squad << 2)] = v;
          *(s4v*)&lA1[srow * 40 + (squad << 2)] = v;
        } else {
          const size_t ro = (size_t)(m0 + srow) * 512 + ((kt - 16) << 5) + (squad << 2);
          *(s4v*)&lA0[srow * 40 + (squad << 2)] = *(const s4v*)&p.A2h[ro];
          *(s4v*)&lA1[srow * 40 + (squad << 2)] = *(const s4v*)&p.A2g[ro];
        }
        __syncthreads();
        const s8v a1 = *(const s8v*)&lA0[arow * 40 + k8];
        const s8v a2 = *(const s8v*)&lA1[arow * 40 + k8];
#pragma unroll
        for (int n = 0; n < 8; n++) {
          const int ntile = (nt << 4) + (wn << 3) + n;
          const size_t boff = ((((size_t)ntile << 5) + kt) * 64 + lane) << 3;
          ac1[n] = MFMA(a1, *(const s8v*)(p.WZf + boff), ac1[n]);
          ac2[n] = MFMA(a2, *(const s8v*)(p.WHf + boff), ac2[n]);
        }
        __syncthreads();
      }
#pragma unroll
      for (int q = 0; q < 4; q++) {
        const int row = (wm << 4) + ((lane >> 4) << 2) + q;
        const int e = eL[row];
#pragma unroll
        for (int n = 0; n < 8; n++) {
          const int col = (nt << 8) + (wn << 7) + (n << 4) + (lane & 15);
          const size_t off = (size_t)e * 512 + col;
          float zpre = ac1[n][q] + p.wz_b[col];
          float hpre = ac2[n][q] + p.wh_b[col];
          float zz = 1.f / (1.f + __expf(-zpre));
          float e2 = __expf(2.f * hpre);
          float th = 1.f - 2.f / (e2 + 1.f);
          float sumh = p.h[off];
          float hn = (1.f - zz) * sumh + zz * th;
          p.h[off] = hn;
          p.h_bf[off] = f2bf(hn);
        }
      }
      __syncthreads();
    }
    // ---- phase C: u = h_bf @ WUR (stripe rows, written above by this block)
    for (int nt = 0; nt < 2; ++nt) {
      fx4 ac[8];
#pragma unroll
      for (int n = 0; n < 8; n++) { ac[n][0]=0.f; ac[n][1]=0.f; ac[n][2]=0.f; ac[n][3]=0.f; }
      for (int kt = 0; kt < 16; ++kt) {
        const unsigned short* s0 = p.h_bf + (size_t)eL[srow] * 512 + (kt << 5) + (squad << 2);
        *(s4v*)&lA0[srow * 40 + (squad << 2)] = *(const s4v*)s0;
        __syncthreads();
        const s8v a = *(const s8v*)&lA0[arow * 40 + k8];
#pragma unroll
        for (int n = 0; n < 8; n++) {
          const int ntile = (nt << 4) + (wn << 3) + n;
          const size_t boff = ((((size_t)ntile << 4) + kt) * 64 + lane) << 3;
          ac[n] = MFMA(a, *(const s8v*)(p.WUR + boff), ac[n]);
        }
        __syncthreads();
      }
#pragma unroll
      for (int q = 0; q < 4; q++) {
        const int row = (wm << 4) + ((lane >> 4) << 2) + q;
        const int e = eL[row];
#pragma unroll
        for (int n = 0; n < 8; n++) {
          const int col = (nt << 8) + (wn << 7) + (n << 4) + (lane & 15);
          p.u_bf[(size_t)e * 512 + col] = f2bf(ac[n][q]);
        }
      }
      __syncthreads();
    }
  }
}

// ---------------- root (R1-proven) ----------------
__global__ void root_gather_kernel(const int* root_nodes, const int* root_in,
                                   const unsigned short* x_bf, const float* h,
                                   unsigned short* Aroot, int B, int R0) {
  int lane = threadIdx.x & 63;
  int waveId = blockIdx.x * (blockDim.x >> 6) + (threadIdx.x >> 6);
  int totalWaves = gridDim.x * (blockDim.x >> 6);
  for (int b = waveId; b < B; b += totalWaves) {
    int c0 = lane << 3;
    int nd = root_nodes[b];
    *(s8v*)&Aroot[(size_t)b * 1024 + c0] = *(const s8v*)&x_bf[(size_t)nd * HD + c0];
    float s[8];
#pragma unroll
    for (int i = 0; i < 8; i++) s[i] = 0.f;
    for (int t = 0; t < R0; ++t) {
      int e = root_in[b * R0 + t];
      const float4* hp = (const float4*)(h + (size_t)e * HD + c0);
      float4 h0 = hp[0], h1 = hp[1];
      s[0] += h0.x; s[1] += h0.y; s[2] += h0.z; s[3] += h0.w;
      s[4] += h1.x; s[5] += h1.y; s[6] += h1.z; s[7] += h1.w;
    }
    s8v sb;
#pragma unroll
    for (int i = 0; i < 8; i++) sb[i] = (short)f2bf(s[i]);
    *(s8v*)&Aroot[(size_t)b * 1024 + 512 + c0] = sb;
  }
}

__global__ __launch_bounds__(256) void gemm_root_kernel(const unsigned short* Aroot,
                                                        const unsigned short* WO,
                                                        const float* wo_b, float* out, int B) {
  __shared__ unsigned short lA[32 * 40];
  int tid = threadIdx.x, lane = tid & 63, w = tid >> 6;
  int wm = w & 1, wn = w >> 1;
  int bt = blockIdx.x;
  int mt = bt >> 1, nt = bt & 1;
  int m0 = mt << 5;
  fx4 ac[8];
#pragma unroll
  for (int n = 0; n < 8; n++) { ac[n][0]=0.f; ac[n][1]=0.f; ac[n][2]=0.f; ac[n][3]=0.f; }
  int srow = tid >> 3, squad = tid & 7;
  int arow = (wm << 4) | (lane & 15), k8 = (lane >> 4) << 3;
  for (int kt = 0; kt < 32; ++kt) {
    const unsigned short* g = Aroot + (size_t)(m0 + srow) * 1024 + (kt << 5) + (squad << 2);
    *(s4v*)&lA[srow * 40 + (squad << 2)] = *(const s4v*)g;
    __syncthreads();
    s8v a = *(const s8v*)&lA[arow * 40 + k8];
#pragma unroll
    for (int n = 0; n < 8; n++) {
      int ntile = (nt << 4) + (wn << 3) + n;
      size_t boff = ((((size_t)ntile * 32) + kt) * 64 + lane) << 3;
      ac[n] = MFMA(a, *(const s8v*)(WO + boff), ac[n]);
    }
    __syncthreads();
  }
#pragma unroll
  for (int q = 0; q < 4; q++) {
    int row = (wm << 4) + ((lane >> 4) << 2) + q;
    int m = m0 + row;
#pragma unroll
    for (int n = 0; n < 8; n++) {
      int col = (nt << 8) + (wn << 7) + (n << 4) + (lane & 15);
      float v = ac[n][q] + wo_b[col];
      out[(size_t)m * HD + col] = v > 0.f ? v : 0.f;
    }
  }
}

extern "C" void kernel_launch(void* const* d_in, const int* in_sizes, int n_in,
                              void* d_out, int out_size, void* d_ws, size_t ws_size,
                              hipStream_t stream) {
  const int* wid = (const int*)d_in[0];
  const int* edge_src = (const int*)d_in[1];
  const int* preds = (const int*)d_in[2];
  const int* root_in = (const int*)d_in[4];
  const int* root_nodes = (const int*)d_in[5];
  const float* emb = (const float*)d_in[6];
  const float* w_r = (const float*)d_in[7];
  const float* ur_w = (const float*)d_in[8];
  const float* ur_b = (const float*)d_in[9];
  const float* wz_w = (const float*)d_in[10];
  const float* wz_b = (const float*)d_in[11];
  const float* wh_w = (const float*)d_in[12];
  const float* wh_b = (const float*)d_in[13];
  const float* wo_w = (const float*)d_in[14];
  const float* wo_b = (const float*)d_in[15];

  const int BN = in_sizes[0];
  const int E = in_sizes[1];
  const int Bt = in_sizes[5];
  const int Epc = E / Bt;
  const int P = in_sizes[2] / (E + 1);
  const int R0 = in_sizes[4] / Bt;

  float* h = (float*)d_out;

  char* wp = (char*)d_ws;
  auto alloc = [&](size_t bytes) {
    char* r = wp;
    wp += (bytes + 255) & ~(size_t)255;
    return r;
  };
  unsigned short* x_bf = (unsigned short*)alloc((size_t)BN * 512 * 2);
  unsigned short* XR = (unsigned short*)alloc((size_t)BN * 512 * 2);
  unsigned short* h_bf = (unsigned short*)alloc((size_t)E * 512 * 2);
  unsigned short* u_bf = (unsigned short*)alloc((size_t)E * 512 * 2);
  unsigned short* A2h = (unsigned short*)alloc((size_t)E * 512 * 2);
  unsigned short* A2g = (unsigned short*)alloc((size_t)E * 512 * 2);
  unsigned short* WR = (unsigned short*)alloc((size_t)512 * 512 * 2);
  unsigned short* WUR = (unsigned short*)alloc((size_t)512 * 512 * 2);
  unsigned short* WZf = (unsigned short*)alloc((size_t)1024 * 512 * 2);
  unsigned short* WHf = (unsigned short*)alloc((size_t)1024 * 512 * 2);
  unsigned short* WO = (unsigned short*)alloc((size_t)1024 * 512 * 2);
  unsigned short* Aroot = (unsigned short*)alloc((size_t)Bt * 1024 * 2);
  int* sched = (int*)alloc(8192);

  hipLaunchKernelGGL(pack_kernel, dim3(512), dim3(256), 0, stream,
                     w_r, ur_w, wz_w, wh_w, wo_w, WR, WUR, WZf, WHf, WO);
  hipLaunchKernelGGL(embed_kernel, dim3(1024), dim3(256), 0, stream, wid, emb, x_bf, BN);
  hipLaunchKernelGGL(schedule_kernel, dim3(1), dim3(64), 0, stream, preds, E, Epc, P, sched);
  hipLaunchKernelGGL(gemm_xr_kernel, dim3((BN / 32) * 2), dim3(256), 0, stream, x_bf, WR, XR, BN);

  RP rp;
  rp.sched = sched;
  rp.preds = preds; rp.edge_src = edge_src;
  rp.ur_b = ur_b; rp.wz_b = wz_b; rp.wh_b = wh_b;
  rp.x_bf = x_bf; rp.XR = XR;
  rp.WZf = WZf; rp.WHf = WHf; rp.WUR = WUR;
  rp.A2h = A2h; rp.A2g = A2g;
  rp.h_bf = h_bf; rp.u_bf = u_bf;
  rp.h = h;
  rp.B = Bt; rp.Epc = Epc; rp.P = P; rp.E = E;

  for (int r = 0; r < Epc && r < 31; ++r) {
    hipLaunchKernelGGL(round_kernel, dim3(512), dim3(256), 0, stream, rp, r);
  }

  hipLaunchKernelGGL(root_gather_kernel, dim3(512), dim3(256), 0, stream,
                     root_nodes, root_in, x_bf, h, Aroot, Bt, R0);
  hipLaunchKernelGGL(gemm_root_kernel, dim3((Bt / 32) * 2), dim3(256), 0, stream,
                     Aroot, WO, wo_b, h + (size_t)E * 512, Bt);
}